// Round 13
// baseline (416.823 us; speedup 1.0000x reference)
//
#include <hip/hip_runtime.h>

#define NNODE 16384
#define NEDGE 262144
#define DS    384
#define DZ    128
#define NH    12
#define HD    16
#define HC    192     // NH*HD
#define HPQK  144     // NH*4*3
#define HPV   288     // NH*8*3
#define NCAT  1152    // HC*3 + HPQK*2 + HPV
#define FEAT  2144    // 576 + 12*128 + 32 (12 A-cols + 20 pad)
#define SOUT  384

typedef _Float16 f16;
typedef _Float16 f16x8 __attribute__((ext_vector_type(8)));
typedef _Float16 f16x4 __attribute__((ext_vector_type(4)));
typedef _Float16 f16x2 __attribute__((ext_vector_type(2)));
typedef float    f32x4v __attribute__((ext_vector_type(4)));

#define AS3(p) ((__attribute__((address_space(3))) void*)(p))
#define AS1(p) ((const __attribute__((address_space(1))) void*)(p))
#define WAVE_LDS_FENCE() asm volatile("s_waitcnt lgkmcnt(0)" ::: "memory")

// ---------------- K0: weight prep (fp32 -> fp16, fold Wpair/bpair through Wo) ---------
__global__ void k_prep(const float* __restrict__ Wq, const float* __restrict__ Wk,
                       const float* __restrict__ Wv, const float* __restrict__ Wqp,
                       const float* __restrict__ Wkp, const float* __restrict__ Wvp,
                       const float* __restrict__ bq, const float* __restrict__ bk,
                       const float* __restrict__ bv, const float* __restrict__ bqp,
                       const float* __restrict__ bkp, const float* __restrict__ bvp,
                       const float* __restrict__ Wb, const float* __restrict__ Wo,
                       const float* __restrict__ Wpair, const float* __restrict__ bpair,
                       const float* __restrict__ hw,
                       f16* __restrict__ Wcat, float* __restrict__ bcat,
                       f16* __restrict__ Wb16, f16* __restrict__ M2,
                       float* __restrict__ gamv)
{
    int t = blockIdx.x * 256 + threadIdx.x;
    const int T0 = NCAT * DS;
    const int T1 = T0 + NCAT;
    const int T2 = T1 + 16 * DZ;          // Wb16 padded to 16 rows
    const int T3 = T2 + SOUT * FEAT;
    const int T4 = T3 + NH;
    if (t < T0) {
        int r = t / DS, c = t - r * DS;
        float v;
        if      (r < 192) v = Wq [(r      ) * DS + c];
        else if (r < 384) v = Wk [(r - 192) * DS + c];
        else if (r < 576) v = Wv [(r - 384) * DS + c];
        else if (r < 720) v = Wqp[(r - 576) * DS + c];
        else if (r < 864) v = Wkp[(r - 720) * DS + c];
        else              v = Wvp[(r - 864) * DS + c];
        Wcat[t] = (f16)v;
    } else if (t < T1) {
        int r = t - T0;
        float v;
        if      (r < 192) v = bq [r];
        else if (r < 384) v = bk [r - 192];
        else if (r < 576) v = bv [r - 384];
        else if (r < 720) v = bqp[r - 576];
        else if (r < 864) v = bkp[r - 720];
        else              v = bvp[r - 864];
        bcat[r] = v;
    } else if (t < T2) {
        int q = t - T1;
        Wb16[q] = (q < NH * DZ) ? (f16)Wb[q] : (f16)0.0f;
    } else if (t < T3) {
        int q = t - T2;
        int r = q / FEAT, c = q - r * FEAT;
        float v = 0.f;
        if (c < 576) {
            v = Wo[r * 768 + c];
        } else if (c < 2112) {
            int h = (c - 576) >> 7, cc = (c - 576) & 127;
            float acc = 0.f;
            #pragma unroll
            for (int d = 0; d < 16; ++d)
                acc += Wo[r * 768 + 576 + h * 16 + d] * Wpair[(h * 16 + d) * DZ + cc];
            v = acc;
        } else if (c < 2124) {
            int h = c - 2112;
            float acc = 0.f;
            #pragma unroll
            for (int d = 0; d < 16; ++d)
                acc += Wo[r * 768 + 576 + h * 16 + d] * bpair[h * 16 + d];
            v = acc;
        }
        M2[q] = (f16)v;
    } else if (t < T4) {
        int h = t - T3;
        gamv[h] = -3.67423461f * log1pf(__expf(hw[h]));
    }
}

// ---------------- K1a: convert s to fp16 ----------------
__global__ void k_convert_s(const float4* __restrict__ s4, f16* __restrict__ s16)
{
    int t = blockIdx.x * 256 + threadIdx.x;
    float4 v = s4[t];
    f16x4 o = { (f16)v.x, (f16)v.y, (f16)v.z, (f16)v.w };
    *(f16x4*)(s16 + 4 * (size_t)t) = o;
}

// ---------------- K1b: z -> zout + z16 (all dense, edge order) --------------------
__global__ void k_zcopy(const float4* __restrict__ z4, f16* __restrict__ z16,
                        float4* __restrict__ zout4)
{
    int t = blockIdx.x * 256 + threadIdx.x;   // NEDGE*DZ/4 exactly
    float4 v = z4[t];
    zout4[t] = v;
    f16x4 o = { (f16)v.x, (f16)v.y, (f16)v.z, (f16)v.w };
    *(f16x4*)(z16 + 4 * (size_t)t) = o;
}

// ---------------- K1c: zbias[e][h] = (z.Wb[h] + bb[h]) * sqrt(3)  (MFMA, dense) ---
__global__ __launch_bounds__(256) void k_zbias(const f16* __restrict__ z16,
                                               const f16* __restrict__ Wb16,
                                               const float* __restrict__ bb,
                                               float* __restrict__ zbias)
{
    const int wv = threadIdx.x >> 6, lane = threadIdx.x & 63;
    const int row0 = (blockIdx.x * 4 + wv) * 64;
    f16x8 bf[4];
    #pragma unroll
    for (int ks = 0; ks < 4; ++ks)
        bf[ks] = *(const f16x8*)(Wb16 + (lane & 15) * DZ + ks * 32 + (lane >> 4) * 8);
    #pragma unroll
    for (int tt = 0; tt < 4; ++tt) {
        int ra = row0 + tt * 16 + (lane & 15);
        f32x4v acc = {};
        #pragma unroll
        for (int ks = 0; ks < 4; ++ks) {
            f16x8 af = *(const f16x8*)(z16 + (size_t)ra * DZ + ks * 32 + (lane >> 4) * 8);
            acc = __builtin_amdgcn_mfma_f32_16x16x32_f16(af, bf[ks], acc, 0, 0, 0);
        }
        int col = lane & 15;
        if (col < NH) {
            #pragma unroll
            for (int r = 0; r < 4; ++r) {
                int row = row0 + tt * 16 + (lane >> 4) * 4 + r;
                zbias[(size_t)row * NH + col] = (acc[r] + bb[col]) * 1.73205081f;
            }
        }
    }
}

// ---------------- MFMA GEMM (f16 out), 128x128 tile: for s -> raw16 ---------------
__global__ __launch_bounds__(256) void k_gemm16(const f16* __restrict__ A, const f16* __restrict__ B,
                                                const float* __restrict__ bias, f16* __restrict__ C,
                                                int M, int N, int K)
{
    __shared__ __align__(16) f16 As[128 * 32];
    __shared__ __align__(16) f16 Bs[128 * 32];
    const int tid = threadIdx.x;
    const int wave = tid >> 6, lane = tid & 63;
    const int bm = blockIdx.x, bn = blockIdx.y;
    const int wm = (wave >> 1) * 64, wn = (wave & 1) * 64;
    f32x4v acc[4][4] = {};
    const int srow = wave * 16 + (lane >> 2);
    const int scol = (lane & 3) * 8;
    const f16* gA0 = A + (size_t)(bm * 128 + srow) * K + scol;
    const f16* gA1 = A + (size_t)(bm * 128 + srow + 64) * K + scol;
    const f16* gB0 = B + (size_t)(bn * 128 + srow) * K + scol;
    const f16* gB1 = B + (size_t)(bn * 128 + srow + 64) * K + scol;
    f16* lA0 = As + wave * 512;
    f16* lA1 = As + (wave + 4) * 512;
    f16* lB0 = Bs + wave * 512;
    f16* lB1 = Bs + (wave + 4) * 512;
    const int fr = lane & 15, fc = (lane >> 4) * 8;
    const int nK = K >> 5;
    for (int kk = 0; kk < nK; ++kk) {
        __syncthreads();
        __builtin_amdgcn_global_load_lds(AS1(gA0), AS3(lA0), 16, 0, 0);
        __builtin_amdgcn_global_load_lds(AS1(gA1), AS3(lA1), 16, 0, 0);
        __builtin_amdgcn_global_load_lds(AS1(gB0), AS3(lB0), 16, 0, 0);
        __builtin_amdgcn_global_load_lds(AS1(gB1), AS3(lB1), 16, 0, 0);
        gA0 += 32; gA1 += 32; gB0 += 32; gB1 += 32;
        __syncthreads();
        f16x8 af[4], bf[4];
        #pragma unroll
        for (int mi = 0; mi < 4; ++mi)
            af[mi] = *(const f16x8*)(As + (wm + mi * 16 + fr) * 32 + fc);
        #pragma unroll
        for (int ni = 0; ni < 4; ++ni)
            bf[ni] = *(const f16x8*)(Bs + (wn + ni * 16 + fr) * 32 + fc);
        #pragma unroll
        for (int mi = 0; mi < 4; ++mi)
            #pragma unroll
            for (int ni = 0; ni < 4; ++ni)
                acc[mi][ni] = __builtin_amdgcn_mfma_f32_16x16x32_f16(af[mi], bf[ni], acc[mi][ni], 0, 0, 0);
    }
    const int r0 = bm * 128 + wm + (lane >> 4) * 4;
    const int c0 = bn * 128 + wn + (lane & 15);
    #pragma unroll
    for (int mi = 0; mi < 4; ++mi)
        #pragma unroll
        for (int ni = 0; ni < 4; ++ni) {
            int col = c0 + ni * 16;
            float b = bias[col];
            #pragma unroll
            for (int r = 0; r < 4; ++r) {
                int row = r0 + mi * 16 + r;
                C[(size_t)row * N + col] = (f16)(acc[mi][ni][r] + b);
            }
        }
}

// ---------------- Final GEMM (f32 out), 128x192 tile: feat @ M2^T, N=384 ----------
// BN=192 -> feat read only 2x (R12: 128-tile read it 3x = +70MB).
__global__ __launch_bounds__(256) void k_gemm_out(const f16* __restrict__ A, const f16* __restrict__ B,
                                                  const float* __restrict__ bias, float* __restrict__ C,
                                                  int M, int N, int K)
{
    __shared__ __align__(16) f16 As[128 * 32];
    __shared__ __align__(16) f16 Bs[192 * 32];
    const int tid = threadIdx.x;
    const int wave = tid >> 6, lane = tid & 63;
    const int bm = blockIdx.x, bn = blockIdx.y;
    const int wm = (wave >> 1) * 64, wn = (wave & 1) * 96;
    f32x4v acc[4][6] = {};
    const int lrow = lane >> 2;               // 0..15
    const int scol = (lane & 3) * 8;
    // A staging: 128 rows, wave w covers rows w*16 and 64+w*16
    const f16* gA0 = A + (size_t)(bm * 128 + wave * 16 + lrow) * K + scol;
    const f16* gA1 = A + (size_t)(bm * 128 + 64 + wave * 16 + lrow) * K + scol;
    f16* lA0 = As + (wave * 16) * 32;
    f16* lA1 = As + (64 + wave * 16) * 32;
    // B staging: 192 rows, wave w covers rows w*48 .. w*48+48 (3 wave-loads of 16 rows)
    const f16* gB0 = B + (size_t)(bn * 192 + wave * 48 + lrow) * K + scol;
    const f16* gB1 = B + (size_t)(bn * 192 + wave * 48 + 16 + lrow) * K + scol;
    const f16* gB2 = B + (size_t)(bn * 192 + wave * 48 + 32 + lrow) * K + scol;
    f16* lB0 = Bs + (wave * 48) * 32;
    f16* lB1 = Bs + (wave * 48 + 16) * 32;
    f16* lB2 = Bs + (wave * 48 + 32) * 32;
    const int fr = lane & 15, fc = (lane >> 4) * 8;
    const int nK = K >> 5;
    for (int kk = 0; kk < nK; ++kk) {
        __syncthreads();
        __builtin_amdgcn_global_load_lds(AS1(gA0), AS3(lA0), 16, 0, 0);
        __builtin_amdgcn_global_load_lds(AS1(gA1), AS3(lA1), 16, 0, 0);
        __builtin_amdgcn_global_load_lds(AS1(gB0), AS3(lB0), 16, 0, 0);
        __builtin_amdgcn_global_load_lds(AS1(gB1), AS3(lB1), 16, 0, 0);
        __builtin_amdgcn_global_load_lds(AS1(gB2), AS3(lB2), 16, 0, 0);
        gA0 += 32; gA1 += 32; gB0 += 32; gB1 += 32; gB2 += 32;
        __syncthreads();
        f16x8 af[4], bf[6];
        #pragma unroll
        for (int mi = 0; mi < 4; ++mi)
            af[mi] = *(const f16x8*)(As + (wm + mi * 16 + fr) * 32 + fc);
        #pragma unroll
        for (int ni = 0; ni < 6; ++ni)
            bf[ni] = *(const f16x8*)(Bs + (wn + ni * 16 + fr) * 32 + fc);
        #pragma unroll
        for (int mi = 0; mi < 4; ++mi)
            #pragma unroll
            for (int ni = 0; ni < 6; ++ni)
                acc[mi][ni] = __builtin_amdgcn_mfma_f32_16x16x32_f16(af[mi], bf[ni], acc[mi][ni], 0, 0, 0);
    }
    const int r0 = bm * 128 + wm + (lane >> 4) * 4;
    const int c0 = bn * 192 + wn + (lane & 15);
    #pragma unroll
    for (int mi = 0; mi < 4; ++mi)
        #pragma unroll
        for (int ni = 0; ni < 6; ++ni) {
            int col = c0 + ni * 16;
            float b = bias[col];
            #pragma unroll
            for (int r = 0; r < 4; ++r) {
                int row = r0 + mi * 16 + r;
                C[(size_t)row * N + col] = acc[mi][ni][r] + b;
            }
        }
}

// ---------------- K3: points only (Q/K/V consumed directly from raw16) ------------
__global__ __launch_bounds__(64) void k_nodepost(const f16* __restrict__ raw, const float* __restrict__ fmat,
        f16* __restrict__ QP16, f16* __restrict__ KP16, f16* __restrict__ VP16)
{
    int n = blockIdx.x, l = threadIdx.x;
    const f16* r = raw + (size_t)n * NCAT;
    const float* fp = fmat + (size_t)n * 16;
    float R00 = fp[0], R01 = fp[1], R02 = fp[2],  t0 = fp[3];
    float R10 = fp[4], R11 = fp[5], R12 = fp[6],  t1 = fp[7];
    float R20 = fp[8], R21 = fp[9], R22 = fp[10], t2 = fp[11];
    if (l < 48) {
        const f16* p = r + 576 + 3 * l;
        float x = (float)p[0], y = (float)p[1], zz = (float)p[2];
        QP16[(size_t)n * HPQK + 3 * l + 0] = (f16)(R00 * x + R01 * y + R02 * zz + t0);
        QP16[(size_t)n * HPQK + 3 * l + 1] = (f16)(R10 * x + R11 * y + R12 * zz + t1);
        QP16[(size_t)n * HPQK + 3 * l + 2] = (f16)(R20 * x + R21 * y + R22 * zz + t2);
        const f16* p2 = r + 720 + 3 * l;
        float x2 = (float)p2[0], y2 = (float)p2[1], z2 = (float)p2[2];
        KP16[(size_t)n * HPQK + 3 * l + 0] = (f16)(R00 * x2 + R01 * y2 + R02 * z2 + t0);
        KP16[(size_t)n * HPQK + 3 * l + 1] = (f16)(R10 * x2 + R11 * y2 + R12 * z2 + t1);
        KP16[(size_t)n * HPQK + 3 * l + 2] = (f16)(R20 * x2 + R21 * y2 + R22 * z2 + t2);
    }
    {
        const f16* p = r + 864 + 3 * l;
        float x = (float)p[0], y = (float)p[1], zz = (float)p[2];
        VP16[(size_t)n * HPV + 3 * l + 0] = (f16)(R00 * x + R01 * y + R02 * zz + t0);
        VP16[(size_t)n * HPV + 3 * l + 1] = (f16)(R10 * x + R11 * y + R12 * zz + t1);
        VP16[(size_t)n * HPV + 3 * l + 2] = (f16)(R20 * x + R21 * y + R22 * zz + t2);
    }
    if (l < 32) {
        int tt = 64 + l;
        const f16* p = r + 864 + 3 * tt;
        float x = (float)p[0], y = (float)p[1], zz = (float)p[2];
        VP16[(size_t)n * HPV + 3 * tt + 0] = (f16)(R00 * x + R01 * y + R02 * zz + t0);
        VP16[(size_t)n * HPV + 3 * tt + 1] = (f16)(R10 * x + R11 * y + R12 * zz + t1);
        VP16[(size_t)n * HPV + 3 * tt + 2] = (f16)(R20 * x + R21 * y + R22 * zz + t2);
    }
}

// ---------------- CSR build ----------------
__global__ void k_zero(int* counts, int* cursor) {
    int t = blockIdx.x * 256 + threadIdx.x;
    if (t < NNODE) counts[t] = 0;
    else if (t < 2 * NNODE) cursor[t - NNODE] = 0;
}
__global__ void k_count(const int* __restrict__ ei, int* counts) {
    int e = blockIdx.x * 256 + threadIdx.x;
    if (e < NEDGE) atomicAdd(&counts[ei[2 * e]], 1);
}
__global__ void k_scan(const int* __restrict__ counts, int* __restrict__ rowptr) {
    __shared__ int lds[256];
    int t = threadIdx.x;
    const int per = NNODE / 256;
    int s = 0;
    for (int i = 0; i < per; ++i) s += counts[t * per + i];
    lds[t] = s; __syncthreads();
    for (int off = 1; off < 256; off <<= 1) {
        int v = (t >= off) ? lds[t - off] : 0;
        __syncthreads();
        lds[t] += v;
        __syncthreads();
    }
    int run = (t == 0) ? 0 : lds[t - 1];
    for (int i = 0; i < per; ++i) { rowptr[t * per + i] = run; run += counts[t * per + i]; }
    if (t == 255) rowptr[NNODE] = run;
}
__global__ void k_scatter(const int* __restrict__ ei, const int* __restrict__ rowptr,
                          int* cursor, int* __restrict__ eids, int* __restrict__ jsorted,
                          int* __restrict__ isorted) {
    int e = blockIdx.x * 256 + threadIdx.x;
    if (e < NEDGE) {
        int i = ei[2 * e];
        int pos = rowptr[i] + atomicAdd(&cursor[i], 1);
        eids[pos] = e;
        jsorted[pos] = ei[2 * e + 1];
        isorted[pos] = i;
    }
}

// ---------------- K5a: edge-parallel logits (Q/K direct from raw16) ---------------
__global__ __launch_bounds__(256) void k_logits2(
    const int* __restrict__ eids,
    const int* __restrict__ isorted, const int* __restrict__ jsorted,
    const float* __restrict__ zbias, const f16* __restrict__ raw,
    const f16* __restrict__ QP16, const f16* __restrict__ KP16,
    const float* __restrict__ gamv, float* __restrict__ attn)
{
    const int pos = blockIdx.x * 256 + threadIdx.x;   // NEDGE exactly
    const int i = isorted[pos], j = jsorted[pos];
    const int e = eids[pos];
    const f16x8* qr = (const f16x8*)(raw + (size_t)i * NCAT);          // Q at col 0
    const f16x8* kr = (const f16x8*)(raw + (size_t)j * NCAT + HC);     // K at col 192
    const f16* qpp = QP16 + (size_t)i * HPQK;
    const f16* kpp = KP16 + (size_t)j * HPQK;
    const float4* zbp = (const float4*)(zbias + (size_t)e * NH);
    float4 zb0 = zbp[0], zb1 = zbp[1], zb2 = zbp[2];
    float zb[NH] = { zb0.x, zb0.y, zb0.z, zb0.w, zb1.x, zb1.y, zb1.z, zb1.w,
                     zb2.x, zb2.y, zb2.z, zb2.w };
    float out[NH];
    #pragma unroll
    for (int h = 0; h < NH; ++h) {
        f16x8 q0 = qr[2 * h], q1 = qr[2 * h + 1];
        f16x8 k0 = kr[2 * h], k1 = kr[2 * h + 1];
        float d = 0.f;
        #pragma unroll
        for (int u = 0; u < 8; ++u)
            d += (float)q0[u] * (float)k0[u] + (float)q1[u] * (float)k1[u];
        float pt = 0.f;
        #pragma unroll
        for (int c = 0; c < 3; ++c) {
            f16x4 qpc = *(const f16x4*)(qpp + 12 * h + 4 * c);
            f16x4 kpc = *(const f16x4*)(kpp + 12 * h + 4 * c);
            #pragma unroll
            for (int u = 0; u < 4; ++u) {
                float dd = (float)qpc[u] - (float)kpc[u];
                pt += dd * dd;
            }
        }
        out[h] = 6.92820323f * d + zb[h] + gamv[h] * pt;
    }
    float4* ao = (float4*)(attn + (size_t)pos * NH);
    ao[0] = make_float4(out[0], out[1], out[2], out[3]);
    ao[1] = make_float4(out[4], out[5], out[6], out[7]);
    ao[2] = make_float4(out[8], out[9], out[10], out[11]);
}

// ---------------- K5b: segment softmax (4 nodes/wave, 16 lanes/node) -------------
__global__ __launch_bounds__(256) void k_soft(
    const int* __restrict__ rowptr, const float* __restrict__ attn,
    f16* __restrict__ a16, f16* __restrict__ feat)
{
    const int lane = threadIdx.x & 63, wv = threadIdx.x >> 6;
    const int slot = lane >> 4, el = lane & 15;
    const int n = blockIdx.x * 16 + wv * 4 + slot;
    const int base = rowptr[n], deg = rowptr[n + 1] - base;

    f16* fo = feat + (size_t)n * FEAT;
    fo[2112 + el]      = (f16)((el < NH && deg > 0) ? 1.0f : 0.0f);
    fo[2112 + 16 + el] = (f16)0.0f;

    float lg[NH];
    if (deg <= 16) {
        if (el < deg) {
            const float4* ar = (const float4*)(attn + (size_t)(base + el) * NH);
            float4 a0 = ar[0], a1 = ar[1], a2 = ar[2];
            lg[0]=a0.x; lg[1]=a0.y; lg[2]=a0.z; lg[3]=a0.w;
            lg[4]=a1.x; lg[5]=a1.y; lg[6]=a1.z; lg[7]=a1.w;
            lg[8]=a2.x; lg[9]=a2.y; lg[10]=a2.z; lg[11]=a2.w;
        } else {
            #pragma unroll
            for (int h = 0; h < NH; ++h) lg[h] = -1e30f;
        }
        #pragma unroll
        for (int h = 0; h < NH; ++h) {
            float v = lg[h];
            v = fmaxf(v, __shfl_xor(v, 1));
            v = fmaxf(v, __shfl_xor(v, 2));
            v = fmaxf(v, __shfl_xor(v, 4));
            v = fmaxf(v, __shfl_xor(v, 8));
            float e = __expf(lg[h] - v);
            float ssum = e;
            ssum += __shfl_xor(ssum, 1);
            ssum += __shfl_xor(ssum, 2);
            ssum += __shfl_xor(ssum, 4);
            ssum += __shfl_xor(ssum, 8);
            lg[h] = (ssum > 0.f) ? e / ssum : 0.f;
        }
        if (el < deg) {
            f16x8 o0, o1;
            #pragma unroll
            for (int h = 0; h < 8; ++h) o0[h] = (f16)lg[h];
            #pragma unroll
            for (int h = 8; h < 12; ++h) o1[h - 8] = (f16)lg[h];
            o1[4] = o1[5] = o1[6] = o1[7] = (f16)0.0f;
            f16* ap = a16 + (size_t)(base + el) * 16;
            *(f16x8*)ap = o0;
            *(f16x8*)(ap + 8) = o1;
        }
    } else {
        const int nch = (deg + 15) >> 4;
        float mx[NH];
        #pragma unroll
        for (int h = 0; h < NH; ++h) mx[h] = -1e30f;
        for (int c = 0; c < nch; ++c) {
            int idx = c * 16 + el;
            if (idx < deg) {
                const float4* ar = (const float4*)(attn + (size_t)(base + idx) * NH);
                float4 a0 = ar[0], a1 = ar[1], a2 = ar[2];
                float v[NH] = { a0.x,a0.y,a0.z,a0.w, a1.x,a1.y,a1.z,a1.w, a2.x,a2.y,a2.z,a2.w };
                #pragma unroll
                for (int h = 0; h < NH; ++h) mx[h] = fmaxf(mx[h], v[h]);
            }
        }
        #pragma unroll
        for (int h = 0; h < NH; ++h) {
            float v = mx[h];
            v = fmaxf(v, __shfl_xor(v, 1));
            v = fmaxf(v, __shfl_xor(v, 2));
            v = fmaxf(v, __shfl_xor(v, 4));
            v = fmaxf(v, __shfl_xor(v, 8));
            mx[h] = v;
        }
        float ls[NH] = {};
        for (int c = 0; c < nch; ++c) {
            int idx = c * 16 + el;
            if (idx < deg) {
                const float4* ar = (const float4*)(attn + (size_t)(base + idx) * NH);
                float4 a0 = ar[0], a1 = ar[1], a2 = ar[2];
                float v[NH] = { a0.x,a0.y,a0.z,a0.w, a1.x,a1.y,a1.z,a1.w, a2.x,a2.y,a2.z,a2.w };
                f16x8 o0, o1;
                #pragma unroll
                for (int h = 0; h < NH; ++h) {
                    float e = __expf(v[h] - mx[h]);
                    ls[h] += e;
                    if (h < 8) o0[h] = (f16)e; else o1[h - 8] = (f16)e;
                }
                o1[4] = o1[5] = o1[6] = o1[7] = (f16)0.0f;
                f16* ap = a16 + (size_t)(base + idx) * 16;
                *(f16x8*)ap = o0;
                *(f16x8*)(ap + 8) = o1;
            }
        }
        float il[NH];
        #pragma unroll
        for (int h = 0; h < NH; ++h) {
            float v = ls[h];
            v += __shfl_xor(v, 1);
            v += __shfl_xor(v, 2);
            v += __shfl_xor(v, 4);
            v += __shfl_xor(v, 8);
            il[h] = (v > 0.f) ? 1.0f / v : 0.f;
        }
        for (int c = 0; c < nch; ++c) {
            int idx = c * 16 + el;
            if (idx < deg) {
                f16* ap = a16 + (size_t)(base + idx) * 16;
                f16x8 o0 = *(f16x8*)ap;
                f16x8 o1 = *(f16x8*)(ap + 8);
                #pragma unroll
                for (int h = 0; h < 8; ++h) o0[h] = (f16)((float)o0[h] * il[h]);
                #pragma unroll
                for (int h = 8; h < 12; ++h) o1[h - 8] = (f16)((float)o1[h - 8] * il[h]);
                *(f16x8*)ap = o0;
                *(f16x8*)(ap + 8) = o1;
            }
        }
    }
}

// ---------------- K6a: u aggregation (gather z16 rows via eids) -------------------
__global__ __launch_bounds__(256) void k_aggu(
    const int* __restrict__ rowptr, const int* __restrict__ eids,
    const f16* __restrict__ a16, const f16* __restrict__ z16, f16* __restrict__ feat)
{
    __shared__ f16 ash[4][64 * 16];
    __shared__ int esh[4][64];
    const int wv = threadIdx.x >> 6, lane = threadIdx.x & 63;
    const int n = blockIdx.x * 4 + wv;
    const int base = rowptr[n], deg = rowptr[n + 1] - base;
    float u0[NH] = {}, u1[NH] = {};
    const int nch = (deg + 63) >> 6;
    for (int c = 0; c < nch; ++c) {
        int cl = min(64, deg - c * 64);
        if (lane < cl) {
            size_t pos = (size_t)(base + c * 64 + lane);
            const f16x8* ap = (const f16x8*)(a16 + pos * 16);
            *(f16x8*)&ash[wv][lane * 16] = ap[0];
            *(f16x8*)&ash[wv][lane * 16 + 8] = ap[1];
            esh[wv][lane] = eids[pos];
        }
        WAVE_LDS_FENCE();
        for (int kk = 0; kk < cl; ++kk) {
            int e = esh[wv][kk];
            f16x2 zv = *(const f16x2*)(z16 + (size_t)e * DZ + 2 * lane);
            float z0 = (float)zv[0], z1 = (float)zv[1];
            #pragma unroll
            for (int i = 0; i < 6; ++i) {
                f16x2 a2 = *(const f16x2*)&ash[wv][kk * 16 + 2 * i];
                float a0 = (float)a2[0], a1 = (float)a2[1];
                u0[2 * i]     += a0 * z0; u1[2 * i]     += a0 * z1;
                u0[2 * i + 1] += a1 * z0; u1[2 * i + 1] += a1 * z1;
            }
        }
        WAVE_LDS_FENCE();
    }
    f16* fo = feat + (size_t)n * FEAT + 576;
    #pragma unroll
    for (int h = 0; h < NH; ++h) {
        f16x2 o = { (f16)u0[h], (f16)u1[h] };
        *(f16x2*)(fo + h * DZ + 2 * lane) = o;
    }
}

// ---------------- K6b: o and o_pts aggregation (V direct from raw16) --------------
__global__ __launch_bounds__(256) void k_aggv(
    const int* __restrict__ rowptr, const int* __restrict__ jsorted,
    const f16* __restrict__ a16, const f16* __restrict__ raw,
    const f16* __restrict__ VP16, const float* __restrict__ fmat,
    f16* __restrict__ feat)
{
    __shared__ f16 ash[4][64 * 16];
    __shared__ int jsh[4][64];
    __shared__ float psh[2][HPV];
    const int w4 = threadIdx.x >> 6;        // wave in block 0..3
    const int lane = threadIdx.x & 63;
    const int slot = w4 >> 1;               // node slot 0..1
    const int role = w4 & 1;                // 0: o, 1: pts
    const int n = blockIdx.x * 2 + slot;
    const int base = rowptr[n], deg = rowptr[n + 1] - base;
    const int nch = (deg + 63) >> 6;

    float o0 = 0, o1 = 0, o2 = 0;
    const int hA = lane >> 4, hB = (64 + lane) >> 4, hC2 = (128 + lane) >> 4;
    float acc[5] = {};
    int hk[5];
    #pragma unroll
    for (int k = 0; k < 5; ++k) hk[k] = (k * 64 + lane) / 24;

    for (int c = 0; c < nch; ++c) {
        int cl = min(64, deg - c * 64);
        if (lane < cl) {
            size_t pos = (size_t)(base + c * 64 + lane);
            const f16x8* ap = (const f16x8*)(a16 + pos * 16);
            *(f16x8*)&ash[w4][lane * 16] = ap[0];
            *(f16x8*)&ash[w4][lane * 16 + 8] = ap[1];
            jsh[w4][lane] = jsorted[pos];
        }
        WAVE_LDS_FENCE();
        if (role == 0) {
            for (int kk = 0; kk < cl; ++kk) {
                int j = jsh[w4][kk];
                const f16* vr = raw + (size_t)j * NCAT + 2 * HC;   // V at col 384
                float aA = (float)ash[w4][kk * 16 + hA];
                float aB = (float)ash[w4][kk * 16 + hB];
                float aC = (float)ash[w4][kk * 16 + hC2];
                o0 += aA * (float)vr[lane];
                o1 += aB * (float)vr[64 + lane];
                o2 += aC * (float)vr[128 + lane];
            }
        } else {
            for (int kk = 0; kk < cl; ++kk) {
                int j = jsh[w4][kk];
                const f16* vp = VP16 + (size_t)j * HPV;
                #pragma unroll
                for (int k = 0; k < 4; ++k)
                    acc[k] += (float)ash[w4][kk * 16 + hk[k]] * (float)vp[k * 64 + lane];
                if (lane < 32)
                    acc[4] += (float)ash[w4][kk * 16 + hk[4]] * (float)vp[256 + lane];
            }
        }
        WAVE_LDS_FENCE();
    }

    f16* fo = feat + (size_t)n * FEAT;
    if (role == 0) {
        fo[lane] = (f16)o0; fo[64 + lane] = (f16)o1; fo[128 + lane] = (f16)o2;
    } else {
        #pragma unroll
        for (int k = 0; k < 4; ++k) psh[slot][k * 64 + lane] = acc[k];
        if (lane < 32) psh[slot][256 + lane] = acc[4];
        WAVE_LDS_FENCE();
        const float* fp = fmat + (size_t)n * 16;
        float R00 = fp[0], R01 = fp[1], R02 = fp[2],  t0 = fp[3];
        float R10 = fp[4], R11 = fp[5], R12 = fp[6],  t1 = fp[7];
        float R20 = fp[8], R21 = fp[9], R22 = fp[10], t2 = fp[11];
        {
            int P = lane;
            float gx = psh[slot][3 * P] - t0, gy = psh[slot][3 * P + 1] - t1, gz = psh[slot][3 * P + 2] - t2;
            float lx = R00 * gx + R10 * gy + R20 * gz;
            float ly = R01 * gx + R11 * gy + R21 * gz;
            float lz = R02 * gx + R12 * gy + R22 * gz;
            fo[192 + 3 * P] = (f16)lx; fo[192 + 3 * P + 1] = (f16)ly; fo[192 + 3 * P + 2] = (f16)lz;
            fo[480 + P] = (f16)sqrtf(lx * lx + ly * ly + lz * lz + 1e-8f);
        }
        if (lane < 32) {
            int P = 64 + lane;
            float gx = psh[slot][3 * P] - t0, gy = psh[slot][3 * P + 1] - t1, gz = psh[slot][3 * P + 2] - t2;
            float lx = R00 * gx + R10 * gy + R20 * gz;
            float ly = R01 * gx + R11 * gy + R21 * gz;
            float lz = R02 * gx + R12 * gy + R22 * gz;
            fo[192 + 3 * P] = (f16)lx; fo[192 + 3 * P + 1] = (f16)ly; fo[192 + 3 * P + 2] = (f16)lz;
            fo[480 + P] = (f16)sqrtf(lx * lx + ly * ly + lz * lz + 1e-8f);
        }
    }
}

extern "C" void kernel_launch(void* const* d_in, const int* in_sizes, int n_in,
                              void* d_out, int out_size, void* d_ws, size_t ws_size,
                              hipStream_t stream)
{
    (void)in_sizes; (void)n_in; (void)out_size; (void)ws_size;
    const float* s     = (const float*)d_in[0];
    const float* z     = (const float*)d_in[1];
    const float* fmat  = (const float*)d_in[2];
    const int*   ei    = (const int*)d_in[3];
    const float* Wq    = (const float*)d_in[4];
    const float* bq    = (const float*)d_in[5];
    const float* Wk    = (const float*)d_in[6];
    const float* bk    = (const float*)d_in[7];
    const float* Wv    = (const float*)d_in[8];
    const float* bv    = (const float*)d_in[9];
    const float* Wb    = (const float*)d_in[10];
    const float* bb    = (const float*)d_in[11];
    const float* Wqp   = (const float*)d_in[12];
    const float* bqp   = (const float*)d_in[13];
    const float* Wkp   = (const float*)d_in[14];
    const float* bkp   = (const float*)d_in[15];
    const float* Wvp   = (const float*)d_in[16];
    const float* bvp   = (const float*)d_in[17];
    const float* hw    = (const float*)d_in[18];
    const float* Wpair = (const float*)d_in[19];
    const float* bpair = (const float*)d_in[20];
    const float* Wo    = (const float*)d_in[21];
    const float* bo    = (const float*)d_in[22];

    // ---- workspace partition (all transients in d_ws; no aliasing) ----
    char* w = (char*)d_ws;
    auto alloc = [&](size_t bytes) { char* p = w; w += (bytes + 255) & ~(size_t)255; return p; };
    f16*   s16     = (f16*)  alloc((size_t)NNODE * DS * 2);
    f16*   Wcat    = (f16*)  alloc((size_t)NCAT * DS * 2);
    float* bcat    = (float*)alloc((size_t)NCAT * 4);
    f16*   Wb16    = (f16*)  alloc((size_t)16 * DZ * 2);
    f16*   M2      = (f16*)  alloc((size_t)SOUT * FEAT * 2);
    float* gamv    = (float*)alloc((size_t)NH * 4);
    int*   counts  = (int*)  alloc((size_t)NNODE * 4);
    int*   rowptr  = (int*)  alloc((size_t)(NNODE + 1) * 4);
    int*   cursor  = (int*)  alloc((size_t)NNODE * 4);
    int*   eids    = (int*)  alloc((size_t)NEDGE * 4);
    int*   jsorted = (int*)  alloc((size_t)NEDGE * 4);
    int*   isorted = (int*)  alloc((size_t)NEDGE * 4);
    float* attn    = (float*)alloc((size_t)NEDGE * NH * 4);
    f16*   z16     = (f16*)  alloc((size_t)NEDGE * DZ * 2);
    float* zbias   = (float*)alloc((size_t)NEDGE * NH * 4);
    f16*   QP16    = (f16*)  alloc((size_t)NNODE * HPQK * 2);
    f16*   KP16    = (f16*)  alloc((size_t)NNODE * HPQK * 2);
    f16*   VP16    = (f16*)  alloc((size_t)NNODE * HPV * 2);
    f16*   a16     = (f16*)  alloc((size_t)NEDGE * 16 * 2);
    f16*   raw16   = (f16*)  alloc((size_t)NNODE * NCAT * 2);   // no union (consumed late)
    f16*   feat    = (f16*)  alloc((size_t)NNODE * FEAT * 2);

    float* zout = (float*)d_out + (size_t)NNODE * DS;

    const int PREP_T = NCAT * DS + NCAT + 16 * DZ + SOUT * FEAT + NH;
    k_prep<<<(PREP_T + 255) / 256, 256, 0, stream>>>(Wq, Wk, Wv, Wqp, Wkp, Wvp,
        bq, bk, bv, bqp, bkp, bvp, Wb, Wo, Wpair, bpair, hw, Wcat, bcat, Wb16, M2, gamv);
    k_zero<<<(2 * NNODE) / 256, 256, 0, stream>>>(counts, cursor);
    k_count<<<NEDGE / 256, 256, 0, stream>>>(ei, counts);
    k_scan<<<1, 256, 0, stream>>>(counts, rowptr);
    k_scatter<<<NEDGE / 256, 256, 0, stream>>>(ei, rowptr, cursor, eids, jsorted, isorted);
    k_convert_s<<<(NNODE * DS / 4) / 256, 256, 0, stream>>>((const float4*)s, s16);
    k_zcopy<<<(NEDGE * DZ / 4) / 256, 256, 0, stream>>>((const float4*)z, z16, (float4*)zout);
    k_zbias<<<NEDGE / 256, 256, 0, stream>>>(z16, Wb16, bb, zbias);
    k_gemm16<<<dim3(NNODE / 128, NCAT / 128), 256, 0, stream>>>(s16, Wcat, bcat, raw16,
        NNODE, NCAT, DS);
    k_nodepost<<<NNODE, 64, 0, stream>>>(raw16, fmat, QP16, KP16, VP16);
    k_logits2<<<NEDGE / 256, 256, 0, stream>>>(eids, isorted, jsorted, zbias, raw16,
        QP16, KP16, gamv, attn);
    k_soft<<<NNODE / 16, 256, 0, stream>>>(rowptr, attn, a16, feat);
    k_aggu<<<NNODE / 4, 256, 0, stream>>>(rowptr, eids, a16, z16, feat);
    k_aggv<<<NNODE / 2, 256, 0, stream>>>(rowptr, jsorted, a16, raw16, VP16, fmat, feat);
    k_gemm_out<<<dim3(NNODE / 128, SOUT / 192), 256, 0, stream>>>(feat, M2, bo, (float*)d_out,
        NNODE, SOUT, FEAT);
}

// Round 14
// 404.586 us; speedup vs baseline: 1.0302x; 1.0302x over previous
//
#include <hip/hip_runtime.h>

#define NNODE 16384
#define NEDGE 262144
#define DS    384
#define DZ    128
#define NH    12
#define HD    16
#define HC    192     // NH*HD
#define HPQK  144     // NH*4*3
#define HPV   288     // NH*8*3
#define NCAT  1152    // HC*3 + HPQK*2 + HPV
#define FEAT  2144    // 576 + 12*128 + 32 (12 A-cols + 20 pad)
#define SOUT  384

typedef _Float16 f16;
typedef _Float16 f16x8 __attribute__((ext_vector_type(8)));
typedef _Float16 f16x4 __attribute__((ext_vector_type(4)));
typedef _Float16 f16x2 __attribute__((ext_vector_type(2)));
typedef float    f32x4v __attribute__((ext_vector_type(4)));

#define AS3(p) ((__attribute__((address_space(3))) void*)(p))
#define AS1(p) ((const __attribute__((address_space(1))) void*)(p))
#define WAVE_LDS_FENCE() asm volatile("s_waitcnt lgkmcnt(0)" ::: "memory")

// ---------------- K0: weight prep (fp32 -> fp16, fold Wpair/bpair through Wo) ---------
__global__ void k_prep(const float* __restrict__ Wq, const float* __restrict__ Wk,
                       const float* __restrict__ Wv, const float* __restrict__ Wqp,
                       const float* __restrict__ Wkp, const float* __restrict__ Wvp,
                       const float* __restrict__ bq, const float* __restrict__ bk,
                       const float* __restrict__ bv, const float* __restrict__ bqp,
                       const float* __restrict__ bkp, const float* __restrict__ bvp,
                       const float* __restrict__ Wb, const float* __restrict__ Wo,
                       const float* __restrict__ Wpair, const float* __restrict__ bpair,
                       const float* __restrict__ hw,
                       f16* __restrict__ Wcat, float* __restrict__ bcat,
                       f16* __restrict__ Wb16, f16* __restrict__ M2,
                       float* __restrict__ gamv)
{
    int t = blockIdx.x * 256 + threadIdx.x;
    const int T0 = NCAT * DS;
    const int T1 = T0 + NCAT;
    const int T2 = T1 + 16 * DZ;          // Wb16 padded to 16 rows
    const int T3 = T2 + SOUT * FEAT;
    const int T4 = T3 + NH;
    if (t < T0) {
        int r = t / DS, c = t - r * DS;
        float v;
        if      (r < 192) v = Wq [(r      ) * DS + c];
        else if (r < 384) v = Wk [(r - 192) * DS + c];
        else if (r < 576) v = Wv [(r - 384) * DS + c];
        else if (r < 720) v = Wqp[(r - 576) * DS + c];
        else if (r < 864) v = Wkp[(r - 720) * DS + c];
        else              v = Wvp[(r - 864) * DS + c];
        Wcat[t] = (f16)v;
    } else if (t < T1) {
        int r = t - T0;
        float v;
        if      (r < 192) v = bq [r];
        else if (r < 384) v = bk [r - 192];
        else if (r < 576) v = bv [r - 384];
        else if (r < 720) v = bqp[r - 576];
        else if (r < 864) v = bkp[r - 720];
        else              v = bvp[r - 864];
        bcat[r] = v;
    } else if (t < T2) {
        int q = t - T1;
        Wb16[q] = (q < NH * DZ) ? (f16)Wb[q] : (f16)0.0f;
    } else if (t < T3) {
        int q = t - T2;
        int r = q / FEAT, c = q - r * FEAT;
        float v = 0.f;
        if (c < 576) {
            v = Wo[r * 768 + c];
        } else if (c < 2112) {
            int h = (c - 576) >> 7, cc = (c - 576) & 127;
            float acc = 0.f;
            #pragma unroll
            for (int d = 0; d < 16; ++d)
                acc += Wo[r * 768 + 576 + h * 16 + d] * Wpair[(h * 16 + d) * DZ + cc];
            v = acc;
        } else if (c < 2124) {
            int h = c - 2112;
            float acc = 0.f;
            #pragma unroll
            for (int d = 0; d < 16; ++d)
                acc += Wo[r * 768 + 576 + h * 16 + d] * bpair[h * 16 + d];
            v = acc;
        }
        M2[q] = (f16)v;
    } else if (t < T4) {
        int h = t - T3;
        gamv[h] = -3.67423461f * log1pf(__expf(hw[h]));
    }
}

// ---------------- K1a: convert s to fp16 ----------------
__global__ void k_convert_s(const float4* __restrict__ s4, f16* __restrict__ s16)
{
    int t = blockIdx.x * 256 + threadIdx.x;
    float4 v = s4[t];
    f16x4 o = { (f16)v.x, (f16)v.y, (f16)v.z, (f16)v.w };
    *(f16x4*)(s16 + 4 * (size_t)t) = o;
}

// ---------------- K1b: z -> zout + z16 (all dense, edge order) --------------------
__global__ void k_zcopy(const float4* __restrict__ z4, f16* __restrict__ z16,
                        float4* __restrict__ zout4)
{
    int t = blockIdx.x * 256 + threadIdx.x;   // NEDGE*DZ/4 exactly
    float4 v = z4[t];
    zout4[t] = v;
    f16x4 o = { (f16)v.x, (f16)v.y, (f16)v.z, (f16)v.w };
    *(f16x4*)(z16 + 4 * (size_t)t) = o;
}

// ---------------- K1c: zbias[e][h] = (z.Wb[h] + bb[h]) * sqrt(3)  (MFMA, dense) ---
__global__ __launch_bounds__(256) void k_zbias(const f16* __restrict__ z16,
                                               const f16* __restrict__ Wb16,
                                               const float* __restrict__ bb,
                                               float* __restrict__ zbias)
{
    const int wv = threadIdx.x >> 6, lane = threadIdx.x & 63;
    const int row0 = (blockIdx.x * 4 + wv) * 64;
    f16x8 bf[4];
    #pragma unroll
    for (int ks = 0; ks < 4; ++ks)
        bf[ks] = *(const f16x8*)(Wb16 + (lane & 15) * DZ + ks * 32 + (lane >> 4) * 8);
    #pragma unroll
    for (int tt = 0; tt < 4; ++tt) {
        int ra = row0 + tt * 16 + (lane & 15);
        f32x4v acc = {};
        #pragma unroll
        for (int ks = 0; ks < 4; ++ks) {
            f16x8 af = *(const f16x8*)(z16 + (size_t)ra * DZ + ks * 32 + (lane >> 4) * 8);
            acc = __builtin_amdgcn_mfma_f32_16x16x32_f16(af, bf[ks], acc, 0, 0, 0);
        }
        int col = lane & 15;
        if (col < NH) {
            #pragma unroll
            for (int r = 0; r < 4; ++r) {
                int row = row0 + tt * 16 + (lane >> 4) * 4 + r;
                zbias[(size_t)row * NH + col] = (acc[r] + bb[col]) * 1.73205081f;
            }
        }
    }
}

// ---------------- MFMA GEMM (f32 out), 128x128 tile ----------------
__global__ __launch_bounds__(256) void k_gemm(const f16* __restrict__ A, const f16* __restrict__ B,
                                              const float* __restrict__ bias, float* __restrict__ C,
                                              int M, int N, int K)
{
    __shared__ __align__(16) f16 As[128 * 32];
    __shared__ __align__(16) f16 Bs[128 * 32];
    const int tid = threadIdx.x;
    const int wave = tid >> 6, lane = tid & 63;
    const int bm = blockIdx.x, bn = blockIdx.y;
    const int wm = (wave >> 1) * 64, wn = (wave & 1) * 64;
    f32x4v acc[4][4] = {};
    const int srow = wave * 16 + (lane >> 2);
    const int scol = (lane & 3) * 8;
    const f16* gA0 = A + (size_t)(bm * 128 + srow) * K + scol;
    const f16* gA1 = A + (size_t)(bm * 128 + srow + 64) * K + scol;
    const f16* gB0 = B + (size_t)(bn * 128 + srow) * K + scol;
    const f16* gB1 = B + (size_t)(bn * 128 + srow + 64) * K + scol;
    f16* lA0 = As + wave * 512;
    f16* lA1 = As + (wave + 4) * 512;
    f16* lB0 = Bs + wave * 512;
    f16* lB1 = Bs + (wave + 4) * 512;
    const int fr = lane & 15, fc = (lane >> 4) * 8;
    const int nK = K >> 5;
    for (int kk = 0; kk < nK; ++kk) {
        __syncthreads();
        __builtin_amdgcn_global_load_lds(AS1(gA0), AS3(lA0), 16, 0, 0);
        __builtin_amdgcn_global_load_lds(AS1(gA1), AS3(lA1), 16, 0, 0);
        __builtin_amdgcn_global_load_lds(AS1(gB0), AS3(lB0), 16, 0, 0);
        __builtin_amdgcn_global_load_lds(AS1(gB1), AS3(lB1), 16, 0, 0);
        gA0 += 32; gA1 += 32; gB0 += 32; gB1 += 32;
        __syncthreads();
        f16x8 af[4], bf[4];
        #pragma unroll
        for (int mi = 0; mi < 4; ++mi)
            af[mi] = *(const f16x8*)(As + (wm + mi * 16 + fr) * 32 + fc);
        #pragma unroll
        for (int ni = 0; ni < 4; ++ni)
            bf[ni] = *(const f16x8*)(Bs + (wn + ni * 16 + fr) * 32 + fc);
        #pragma unroll
        for (int mi = 0; mi < 4; ++mi)
            #pragma unroll
            for (int ni = 0; ni < 4; ++ni)
                acc[mi][ni] = __builtin_amdgcn_mfma_f32_16x16x32_f16(af[mi], bf[ni], acc[mi][ni], 0, 0, 0);
    }
    const int r0 = bm * 128 + wm + (lane >> 4) * 4;
    const int c0 = bn * 128 + wn + (lane & 15);
    #pragma unroll
    for (int mi = 0; mi < 4; ++mi)
        #pragma unroll
        for (int ni = 0; ni < 4; ++ni) {
            int col = c0 + ni * 16;
            float b = bias[col];
            #pragma unroll
            for (int r = 0; r < 4; ++r) {
                int row = r0 + mi * 16 + r;
                C[(size_t)row * N + col] = acc[mi][ni][r] + b;
            }
        }
}

// ---------------- MFMA GEMM (f16 out), 128x128 tile: for s -> raw16 ---------------
__global__ __launch_bounds__(256) void k_gemm16(const f16* __restrict__ A, const f16* __restrict__ B,
                                                const float* __restrict__ bias, f16* __restrict__ C,
                                                int M, int N, int K)
{
    __shared__ __align__(16) f16 As[128 * 32];
    __shared__ __align__(16) f16 Bs[128 * 32];
    const int tid = threadIdx.x;
    const int wave = tid >> 6, lane = tid & 63;
    const int bm = blockIdx.x, bn = blockIdx.y;
    const int wm = (wave >> 1) * 64, wn = (wave & 1) * 64;
    f32x4v acc[4][4] = {};
    const int srow = wave * 16 + (lane >> 2);
    const int scol = (lane & 3) * 8;
    const f16* gA0 = A + (size_t)(bm * 128 + srow) * K + scol;
    const f16* gA1 = A + (size_t)(bm * 128 + srow + 64) * K + scol;
    const f16* gB0 = B + (size_t)(bn * 128 + srow) * K + scol;
    const f16* gB1 = B + (size_t)(bn * 128 + srow + 64) * K + scol;
    f16* lA0 = As + wave * 512;
    f16* lA1 = As + (wave + 4) * 512;
    f16* lB0 = Bs + wave * 512;
    f16* lB1 = Bs + (wave + 4) * 512;
    const int fr = lane & 15, fc = (lane >> 4) * 8;
    const int nK = K >> 5;
    for (int kk = 0; kk < nK; ++kk) {
        __syncthreads();
        __builtin_amdgcn_global_load_lds(AS1(gA0), AS3(lA0), 16, 0, 0);
        __builtin_amdgcn_global_load_lds(AS1(gA1), AS3(lA1), 16, 0, 0);
        __builtin_amdgcn_global_load_lds(AS1(gB0), AS3(lB0), 16, 0, 0);
        __builtin_amdgcn_global_load_lds(AS1(gB1), AS3(lB1), 16, 0, 0);
        gA0 += 32; gA1 += 32; gB0 += 32; gB1 += 32;
        __syncthreads();
        f16x8 af[4], bf[4];
        #pragma unroll
        for (int mi = 0; mi < 4; ++mi)
            af[mi] = *(const f16x8*)(As + (wm + mi * 16 + fr) * 32 + fc);
        #pragma unroll
        for (int ni = 0; ni < 4; ++ni)
            bf[ni] = *(const f16x8*)(Bs + (wn + ni * 16 + fr) * 32 + fc);
        #pragma unroll
        for (int mi = 0; mi < 4; ++mi)
            #pragma unroll
            for (int ni = 0; ni < 4; ++ni)
                acc[mi][ni] = __builtin_amdgcn_mfma_f32_16x16x32_f16(af[mi], bf[ni], acc[mi][ni], 0, 0, 0);
    }
    const int r0 = bm * 128 + wm + (lane >> 4) * 4;
    const int c0 = bn * 128 + wn + (lane & 15);
    #pragma unroll
    for (int mi = 0; mi < 4; ++mi)
        #pragma unroll
        for (int ni = 0; ni < 4; ++ni) {
            int col = c0 + ni * 16;
            float b = bias[col];
            #pragma unroll
            for (int r = 0; r < 4; ++r) {
                int row = r0 + mi * 16 + r;
                C[(size_t)row * N + col] = (f16)(acc[mi][ni][r] + b);
            }
        }
}

// ---------------- K3: points only (Q/K/V consumed directly from raw16) ------------
__global__ __launch_bounds__(64) void k_nodepost(const f16* __restrict__ raw, const float* __restrict__ fmat,
        f16* __restrict__ QP16, f16* __restrict__ KP16, f16* __restrict__ VP16)
{
    int n = blockIdx.x, l = threadIdx.x;
    const f16* r = raw + (size_t)n * NCAT;
    const float* fp = fmat + (size_t)n * 16;
    float R00 = fp[0], R01 = fp[1], R02 = fp[2],  t0 = fp[3];
    float R10 = fp[4], R11 = fp[5], R12 = fp[6],  t1 = fp[7];
    float R20 = fp[8], R21 = fp[9], R22 = fp[10], t2 = fp[11];
    if (l < 48) {
        const f16* p = r + 576 + 3 * l;
        float x = (float)p[0], y = (float)p[1], zz = (float)p[2];
        QP16[(size_t)n * HPQK + 3 * l + 0] = (f16)(R00 * x + R01 * y + R02 * zz + t0);
        QP16[(size_t)n * HPQK + 3 * l + 1] = (f16)(R10 * x + R11 * y + R12 * zz + t1);
        QP16[(size_t)n * HPQK + 3 * l + 2] = (f16)(R20 * x + R21 * y + R22 * zz + t2);
        const f16* p2 = r + 720 + 3 * l;
        float x2 = (float)p2[0], y2 = (float)p2[1], z2 = (float)p2[2];
        KP16[(size_t)n * HPQK + 3 * l + 0] = (f16)(R00 * x2 + R01 * y2 + R02 * z2 + t0);
        KP16[(size_t)n * HPQK + 3 * l + 1] = (f16)(R10 * x2 + R11 * y2 + R12 * z2 + t1);
        KP16[(size_t)n * HPQK + 3 * l + 2] = (f16)(R20 * x2 + R21 * y2 + R22 * z2 + t2);
    }
    {
        const f16* p = r + 864 + 3 * l;
        float x = (float)p[0], y = (float)p[1], zz = (float)p[2];
        VP16[(size_t)n * HPV + 3 * l + 0] = (f16)(R00 * x + R01 * y + R02 * zz + t0);
        VP16[(size_t)n * HPV + 3 * l + 1] = (f16)(R10 * x + R11 * y + R12 * zz + t1);
        VP16[(size_t)n * HPV + 3 * l + 2] = (f16)(R20 * x + R21 * y + R22 * zz + t2);
    }
    if (l < 32) {
        int tt = 64 + l;
        const f16* p = r + 864 + 3 * tt;
        float x = (float)p[0], y = (float)p[1], zz = (float)p[2];
        VP16[(size_t)n * HPV + 3 * tt + 0] = (f16)(R00 * x + R01 * y + R02 * zz + t0);
        VP16[(size_t)n * HPV + 3 * tt + 1] = (f16)(R10 * x + R11 * y + R12 * zz + t1);
        VP16[(size_t)n * HPV + 3 * tt + 2] = (f16)(R20 * x + R21 * y + R22 * zz + t2);
    }
}

// ---------------- CSR build ----------------
__global__ void k_zero(int* counts, int* cursor) {
    int t = blockIdx.x * 256 + threadIdx.x;
    if (t < NNODE) counts[t] = 0;
    else if (t < 2 * NNODE) cursor[t - NNODE] = 0;
}
__global__ void k_count(const int* __restrict__ ei, int* counts) {
    int e = blockIdx.x * 256 + threadIdx.x;
    if (e < NEDGE) atomicAdd(&counts[ei[2 * e]], 1);
}
__global__ void k_scan(const int* __restrict__ counts, int* __restrict__ rowptr) {
    __shared__ int lds[256];
    int t = threadIdx.x;
    const int per = NNODE / 256;
    int s = 0;
    for (int i = 0; i < per; ++i) s += counts[t * per + i];
    lds[t] = s; __syncthreads();
    for (int off = 1; off < 256; off <<= 1) {
        int v = (t >= off) ? lds[t - off] : 0;
        __syncthreads();
        lds[t] += v;
        __syncthreads();
    }
    int run = (t == 0) ? 0 : lds[t - 1];
    for (int i = 0; i < per; ++i) { rowptr[t * per + i] = run; run += counts[t * per + i]; }
    if (t == 255) rowptr[NNODE] = run;
}
__global__ void k_scatter(const int* __restrict__ ei, const int* __restrict__ rowptr,
                          int* cursor, int* __restrict__ eids, int* __restrict__ jsorted,
                          int* __restrict__ isorted) {
    int e = blockIdx.x * 256 + threadIdx.x;
    if (e < NEDGE) {
        int i = ei[2 * e];
        int pos = rowptr[i] + atomicAdd(&cursor[i], 1);
        eids[pos] = e;
        jsorted[pos] = ei[2 * e + 1];
        isorted[pos] = i;
    }
}

// ---------------- K5a: edge-parallel logits (Q/K direct from raw16) ---------------
__global__ __launch_bounds__(256) void k_logits2(
    const int* __restrict__ eids,
    const int* __restrict__ isorted, const int* __restrict__ jsorted,
    const float* __restrict__ zbias, const f16* __restrict__ raw,
    const f16* __restrict__ QP16, const f16* __restrict__ KP16,
    const float* __restrict__ gamv, float* __restrict__ attn)
{
    const int pos = blockIdx.x * 256 + threadIdx.x;   // NEDGE exactly
    const int i = isorted[pos], j = jsorted[pos];
    const int e = eids[pos];
    const f16x8* qr = (const f16x8*)(raw + (size_t)i * NCAT);          // Q at col 0
    const f16x8* kr = (const f16x8*)(raw + (size_t)j * NCAT + HC);     // K at col 192
    const f16* qpp = QP16 + (size_t)i * HPQK;
    const f16* kpp = KP16 + (size_t)j * HPQK;
    const float4* zbp = (const float4*)(zbias + (size_t)e * NH);
    float4 zb0 = zbp[0], zb1 = zbp[1], zb2 = zbp[2];
    float zb[NH] = { zb0.x, zb0.y, zb0.z, zb0.w, zb1.x, zb1.y, zb1.z, zb1.w,
                     zb2.x, zb2.y, zb2.z, zb2.w };
    float out[NH];
    #pragma unroll
    for (int h = 0; h < NH; ++h) {
        f16x8 q0 = qr[2 * h], q1 = qr[2 * h + 1];
        f16x8 k0 = kr[2 * h], k1 = kr[2 * h + 1];
        float d = 0.f;
        #pragma unroll
        for (int u = 0; u < 8; ++u)
            d += (float)q0[u] * (float)k0[u] + (float)q1[u] * (float)k1[u];
        float pt = 0.f;
        #pragma unroll
        for (int c = 0; c < 3; ++c) {
            f16x4 qpc = *(const f16x4*)(qpp + 12 * h + 4 * c);
            f16x4 kpc = *(const f16x4*)(kpp + 12 * h + 4 * c);
            #pragma unroll
            for (int u = 0; u < 4; ++u) {
                float dd = (float)qpc[u] - (float)kpc[u];
                pt += dd * dd;
            }
        }
        out[h] = 6.92820323f * d + zb[h] + gamv[h] * pt;
    }
    float4* ao = (float4*)(attn + (size_t)pos * NH);
    ao[0] = make_float4(out[0], out[1], out[2], out[3]);
    ao[1] = make_float4(out[4], out[5], out[6], out[7]);
    ao[2] = make_float4(out[8], out[9], out[10], out[11]);
}

// ---------------- K5b: segment softmax (4 nodes/wave, 16 lanes/node) -------------
__global__ __launch_bounds__(256) void k_soft(
    const int* __restrict__ rowptr, const float* __restrict__ attn,
    f16* __restrict__ a16, f16* __restrict__ feat)
{
    const int lane = threadIdx.x & 63, wv = threadIdx.x >> 6;
    const int slot = lane >> 4, el = lane & 15;
    const int n = blockIdx.x * 16 + wv * 4 + slot;
    const int base = rowptr[n], deg = rowptr[n + 1] - base;

    f16* fo = feat + (size_t)n * FEAT;
    fo[2112 + el]      = (f16)((el < NH && deg > 0) ? 1.0f : 0.0f);
    fo[2112 + 16 + el] = (f16)0.0f;

    float lg[NH];
    if (deg <= 16) {
        if (el < deg) {
            const float4* ar = (const float4*)(attn + (size_t)(base + el) * NH);
            float4 a0 = ar[0], a1 = ar[1], a2 = ar[2];
            lg[0]=a0.x; lg[1]=a0.y; lg[2]=a0.z; lg[3]=a0.w;
            lg[4]=a1.x; lg[5]=a1.y; lg[6]=a1.z; lg[7]=a1.w;
            lg[8]=a2.x; lg[9]=a2.y; lg[10]=a2.z; lg[11]=a2.w;
        } else {
            #pragma unroll
            for (int h = 0; h < NH; ++h) lg[h] = -1e30f;
        }
        #pragma unroll
        for (int h = 0; h < NH; ++h) {
            float v = lg[h];
            v = fmaxf(v, __shfl_xor(v, 1));
            v = fmaxf(v, __shfl_xor(v, 2));
            v = fmaxf(v, __shfl_xor(v, 4));
            v = fmaxf(v, __shfl_xor(v, 8));
            float e = __expf(lg[h] - v);
            float ssum = e;
            ssum += __shfl_xor(ssum, 1);
            ssum += __shfl_xor(ssum, 2);
            ssum += __shfl_xor(ssum, 4);
            ssum += __shfl_xor(ssum, 8);
            lg[h] = (ssum > 0.f) ? e / ssum : 0.f;
        }
        if (el < deg) {
            f16x8 o0, o1;
            #pragma unroll
            for (int h = 0; h < 8; ++h) o0[h] = (f16)lg[h];
            #pragma unroll
            for (int h = 8; h < 12; ++h) o1[h - 8] = (f16)lg[h];
            o1[4] = o1[5] = o1[6] = o1[7] = (f16)0.0f;
            f16* ap = a16 + (size_t)(base + el) * 16;
            *(f16x8*)ap = o0;
            *(f16x8*)(ap + 8) = o1;
        }
    } else {
        const int nch = (deg + 15) >> 4;
        float mx[NH];
        #pragma unroll
        for (int h = 0; h < NH; ++h) mx[h] = -1e30f;
        for (int c = 0; c < nch; ++c) {
            int idx = c * 16 + el;
            if (idx < deg) {
                const float4* ar = (const float4*)(attn + (size_t)(base + idx) * NH);
                float4 a0 = ar[0], a1 = ar[1], a2 = ar[2];
                float v[NH] = { a0.x,a0.y,a0.z,a0.w, a1.x,a1.y,a1.z,a1.w, a2.x,a2.y,a2.z,a2.w };
                #pragma unroll
                for (int h = 0; h < NH; ++h) mx[h] = fmaxf(mx[h], v[h]);
            }
        }
        #pragma unroll
        for (int h = 0; h < NH; ++h) {
            float v = mx[h];
            v = fmaxf(v, __shfl_xor(v, 1));
            v = fmaxf(v, __shfl_xor(v, 2));
            v = fmaxf(v, __shfl_xor(v, 4));
            v = fmaxf(v, __shfl_xor(v, 8));
            mx[h] = v;
        }
        float ls[NH] = {};
        for (int c = 0; c < nch; ++c) {
            int idx = c * 16 + el;
            if (idx < deg) {
                const float4* ar = (const float4*)(attn + (size_t)(base + idx) * NH);
                float4 a0 = ar[0], a1 = ar[1], a2 = ar[2];
                float v[NH] = { a0.x,a0.y,a0.z,a0.w, a1.x,a1.y,a1.z,a1.w, a2.x,a2.y,a2.z,a2.w };
                f16x8 o0, o1;
                #pragma unroll
                for (int h = 0; h < NH; ++h) {
                    float e = __expf(v[h] - mx[h]);
                    ls[h] += e;
                    if (h < 8) o0[h] = (f16)e; else o1[h - 8] = (f16)e;
                }
                o1[4] = o1[5] = o1[6] = o1[7] = (f16)0.0f;
                f16* ap = a16 + (size_t)(base + idx) * 16;
                *(f16x8*)ap = o0;
                *(f16x8*)(ap + 8) = o1;
            }
        }
        float il[NH];
        #pragma unroll
        for (int h = 0; h < NH; ++h) {
            float v = ls[h];
            v += __shfl_xor(v, 1);
            v += __shfl_xor(v, 2);
            v += __shfl_xor(v, 4);
            v += __shfl_xor(v, 8);
            il[h] = (v > 0.f) ? 1.0f / v : 0.f;
        }
        for (int c = 0; c < nch; ++c) {
            int idx = c * 16 + el;
            if (idx < deg) {
                f16* ap = a16 + (size_t)(base + idx) * 16;
                f16x8 o0 = *(f16x8*)ap;
                f16x8 o1 = *(f16x8*)(ap + 8);
                #pragma unroll
                for (int h = 0; h < 8; ++h) o0[h] = (f16)((float)o0[h] * il[h]);
                #pragma unroll
                for (int h = 8; h < 12; ++h) o1[h - 8] = (f16)((float)o1[h - 8] * il[h]);
                *(f16x8*)ap = o0;
                *(f16x8*)(ap + 8) = o1;
            }
        }
    }
}

// ---------------- K6a: u aggregation (gather z16 rows via eids) -------------------
__global__ __launch_bounds__(256) void k_aggu(
    const int* __restrict__ rowptr, const int* __restrict__ eids,
    const f16* __restrict__ a16, const f16* __restrict__ z16, f16* __restrict__ feat)
{
    __shared__ f16 ash[4][64 * 16];
    __shared__ int esh[4][64];
    const int wv = threadIdx.x >> 6, lane = threadIdx.x & 63;
    const int n = blockIdx.x * 4 + wv;
    const int base = rowptr[n], deg = rowptr[n + 1] - base;
    float u0[NH] = {}, u1[NH] = {};
    const int nch = (deg + 63) >> 6;
    for (int c = 0; c < nch; ++c) {
        int cl = min(64, deg - c * 64);
        if (lane < cl) {
            size_t pos = (size_t)(base + c * 64 + lane);
            const f16x8* ap = (const f16x8*)(a16 + pos * 16);
            *(f16x8*)&ash[wv][lane * 16] = ap[0];
            *(f16x8*)&ash[wv][lane * 16 + 8] = ap[1];
            esh[wv][lane] = eids[pos];
        }
        WAVE_LDS_FENCE();
        for (int kk = 0; kk < cl; ++kk) {
            int e = esh[wv][kk];
            f16x2 zv = *(const f16x2*)(z16 + (size_t)e * DZ + 2 * lane);
            float z0 = (float)zv[0], z1 = (float)zv[1];
            #pragma unroll
            for (int i = 0; i < 6; ++i) {
                f16x2 a2 = *(const f16x2*)&ash[wv][kk * 16 + 2 * i];
                float a0 = (float)a2[0], a1 = (float)a2[1];
                u0[2 * i]     += a0 * z0; u1[2 * i]     += a0 * z1;
                u0[2 * i + 1] += a1 * z0; u1[2 * i + 1] += a1 * z1;
            }
        }
        WAVE_LDS_FENCE();
    }
    f16* fo = feat + (size_t)n * FEAT + 576;
    #pragma unroll
    for (int h = 0; h < NH; ++h) {
        f16x2 o = { (f16)u0[h], (f16)u1[h] };
        *(f16x2*)(fo + h * DZ + 2 * lane) = o;
    }
}

// ---------------- K6b: o and o_pts aggregation (V direct from raw16) --------------
__global__ __launch_bounds__(256) void k_aggv(
    const int* __restrict__ rowptr, const int* __restrict__ jsorted,
    const f16* __restrict__ a16, const f16* __restrict__ raw,
    const f16* __restrict__ VP16, const float* __restrict__ fmat,
    f16* __restrict__ feat)
{
    __shared__ f16 ash[4][64 * 16];
    __shared__ int jsh[4][64];
    __shared__ float psh[2][HPV];
    const int w4 = threadIdx.x >> 6;        // wave in block 0..3
    const int lane = threadIdx.x & 63;
    const int slot = w4 >> 1;               // node slot 0..1
    const int role = w4 & 1;                // 0: o, 1: pts
    const int n = blockIdx.x * 2 + slot;
    const int base = rowptr[n], deg = rowptr[n + 1] - base;
    const int nch = (deg + 63) >> 6;

    float o0 = 0, o1 = 0, o2 = 0;
    const int hA = lane >> 4, hB = (64 + lane) >> 4, hC2 = (128 + lane) >> 4;
    float acc[5] = {};
    int hk[5];
    #pragma unroll
    for (int k = 0; k < 5; ++k) hk[k] = (k * 64 + lane) / 24;

    for (int c = 0; c < nch; ++c) {
        int cl = min(64, deg - c * 64);
        if (lane < cl) {
            size_t pos = (size_t)(base + c * 64 + lane);
            const f16x8* ap = (const f16x8*)(a16 + pos * 16);
            *(f16x8*)&ash[w4][lane * 16] = ap[0];
            *(f16x8*)&ash[w4][lane * 16 + 8] = ap[1];
            jsh[w4][lane] = jsorted[pos];
        }
        WAVE_LDS_FENCE();
        if (role == 0) {
            for (int kk = 0; kk < cl; ++kk) {
                int j = jsh[w4][kk];
                const f16* vr = raw + (size_t)j * NCAT + 2 * HC;   // V at col 384
                float aA = (float)ash[w4][kk * 16 + hA];
                float aB = (float)ash[w4][kk * 16 + hB];
                float aC = (float)ash[w4][kk * 16 + hC2];
                o0 += aA * (float)vr[lane];
                o1 += aB * (float)vr[64 + lane];
                o2 += aC * (float)vr[128 + lane];
            }
        } else {
            for (int kk = 0; kk < cl; ++kk) {
                int j = jsh[w4][kk];
                const f16* vp = VP16 + (size_t)j * HPV;
                #pragma unroll
                for (int k = 0; k < 4; ++k)
                    acc[k] += (float)ash[w4][kk * 16 + hk[k]] * (float)vp[k * 64 + lane];
                if (lane < 32)
                    acc[4] += (float)ash[w4][kk * 16 + hk[4]] * (float)vp[256 + lane];
            }
        }
        WAVE_LDS_FENCE();
    }

    f16* fo = feat + (size_t)n * FEAT;
    if (role == 0) {
        fo[lane] = (f16)o0; fo[64 + lane] = (f16)o1; fo[128 + lane] = (f16)o2;
    } else {
        #pragma unroll
        for (int k = 0; k < 4; ++k) psh[slot][k * 64 + lane] = acc[k];
        if (lane < 32) psh[slot][256 + lane] = acc[4];
        WAVE_LDS_FENCE();
        const float* fp = fmat + (size_t)n * 16;
        float R00 = fp[0], R01 = fp[1], R02 = fp[2],  t0 = fp[3];
        float R10 = fp[4], R11 = fp[5], R12 = fp[6],  t1 = fp[7];
        float R20 = fp[8], R21 = fp[9], R22 = fp[10], t2 = fp[11];
        {
            int P = lane;
            float gx = psh[slot][3 * P] - t0, gy = psh[slot][3 * P + 1] - t1, gz = psh[slot][3 * P + 2] - t2;
            float lx = R00 * gx + R10 * gy + R20 * gz;
            float ly = R01 * gx + R11 * gy + R21 * gz;
            float lz = R02 * gx + R12 * gy + R22 * gz;
            fo[192 + 3 * P] = (f16)lx; fo[192 + 3 * P + 1] = (f16)ly; fo[192 + 3 * P + 2] = (f16)lz;
            fo[480 + P] = (f16)sqrtf(lx * lx + ly * ly + lz * lz + 1e-8f);
        }
        if (lane < 32) {
            int P = 64 + lane;
            float gx = psh[slot][3 * P] - t0, gy = psh[slot][3 * P + 1] - t1, gz = psh[slot][3 * P + 2] - t2;
            float lx = R00 * gx + R10 * gy + R20 * gz;
            float ly = R01 * gx + R11 * gy + R21 * gz;
            float lz = R02 * gx + R12 * gy + R22 * gz;
            fo[192 + 3 * P] = (f16)lx; fo[192 + 3 * P + 1] = (f16)ly; fo[192 + 3 * P + 2] = (f16)lz;
            fo[480 + P] = (f16)sqrtf(lx * lx + ly * ly + lz * lz + 1e-8f);
        }
    }
}

extern "C" void kernel_launch(void* const* d_in, const int* in_sizes, int n_in,
                              void* d_out, int out_size, void* d_ws, size_t ws_size,
                              hipStream_t stream)
{
    (void)in_sizes; (void)n_in; (void)out_size; (void)ws_size;
    const float* s     = (const float*)d_in[0];
    const float* z     = (const float*)d_in[1];
    const float* fmat  = (const float*)d_in[2];
    const int*   ei    = (const int*)d_in[3];
    const float* Wq    = (const float*)d_in[4];
    const float* bq    = (const float*)d_in[5];
    const float* Wk    = (const float*)d_in[6];
    const float* bk    = (const float*)d_in[7];
    const float* Wv    = (const float*)d_in[8];
    const float* bv    = (const float*)d_in[9];
    const float* Wb    = (const float*)d_in[10];
    const float* bb    = (const float*)d_in[11];
    const float* Wqp   = (const float*)d_in[12];
    const float* bqp   = (const float*)d_in[13];
    const float* Wkp   = (const float*)d_in[14];
    const float* bkp   = (const float*)d_in[15];
    const float* Wvp   = (const float*)d_in[16];
    const float* bvp   = (const float*)d_in[17];
    const float* hw    = (const float*)d_in[18];
    const float* Wpair = (const float*)d_in[19];
    const float* bpair = (const float*)d_in[20];
    const float* Wo    = (const float*)d_in[21];
    const float* bo    = (const float*)d_in[22];

    // ---- workspace partition (all transients in d_ws; no aliasing) ----
    char* w = (char*)d_ws;
    auto alloc = [&](size_t bytes) { char* p = w; w += (bytes + 255) & ~(size_t)255; return p; };
    f16*   s16     = (f16*)  alloc((size_t)NNODE * DS * 2);
    f16*   Wcat    = (f16*)  alloc((size_t)NCAT * DS * 2);
    float* bcat    = (float*)alloc((size_t)NCAT * 4);
    f16*   Wb16    = (f16*)  alloc((size_t)16 * DZ * 2);
    f16*   M2      = (f16*)  alloc((size_t)SOUT * FEAT * 2);
    float* gamv    = (float*)alloc((size_t)NH * 4);
    int*   counts  = (int*)  alloc((size_t)NNODE * 4);
    int*   rowptr  = (int*)  alloc((size_t)(NNODE + 1) * 4);
    int*   cursor  = (int*)  alloc((size_t)NNODE * 4);
    int*   eids    = (int*)  alloc((size_t)NEDGE * 4);
    int*   jsorted = (int*)  alloc((size_t)NEDGE * 4);
    int*   isorted = (int*)  alloc((size_t)NEDGE * 4);
    float* attn    = (float*)alloc((size_t)NEDGE * NH * 4);
    f16*   z16     = (f16*)  alloc((size_t)NEDGE * DZ * 2);
    float* zbias   = (float*)alloc((size_t)NEDGE * NH * 4);
    f16*   QP16    = (f16*)  alloc((size_t)NNODE * HPQK * 2);
    f16*   KP16    = (f16*)  alloc((size_t)NNODE * HPQK * 2);
    f16*   VP16    = (f16*)  alloc((size_t)NNODE * HPV * 2);
    f16*   a16     = (f16*)  alloc((size_t)NEDGE * 16 * 2);
    f16*   raw16   = (f16*)  alloc((size_t)NNODE * NCAT * 2);
    f16*   feat    = (f16*)  alloc((size_t)NNODE * FEAT * 2);

    float* zout = (float*)d_out + (size_t)NNODE * DS;

    const int PREP_T = NCAT * DS + NCAT + 16 * DZ + SOUT * FEAT + NH;
    k_prep<<<(PREP_T + 255) / 256, 256, 0, stream>>>(Wq, Wk, Wv, Wqp, Wkp, Wvp,
        bq, bk, bv, bqp, bkp, bvp, Wb, Wo, Wpair, bpair, hw, Wcat, bcat, Wb16, M2, gamv);
    k_zero<<<(2 * NNODE) / 256, 256, 0, stream>>>(counts, cursor);
    k_count<<<NEDGE / 256, 256, 0, stream>>>(ei, counts);
    k_scan<<<1, 256, 0, stream>>>(counts, rowptr);
    k_scatter<<<NEDGE / 256, 256, 0, stream>>>(ei, rowptr, cursor, eids, jsorted, isorted);
    k_convert_s<<<(NNODE * DS / 4) / 256, 256, 0, stream>>>((const float4*)s, s16);
    k_zcopy<<<(NEDGE * DZ / 4) / 256, 256, 0, stream>>>((const float4*)z, z16, (float4*)zout);
    k_zbias<<<NEDGE / 256, 256, 0, stream>>>(z16, Wb16, bb, zbias);
    k_gemm16<<<dim3(NNODE / 128, NCAT / 128), 256, 0, stream>>>(s16, Wcat, bcat, raw16,
        NNODE, NCAT, DS);
    k_nodepost<<<NNODE, 64, 0, stream>>>(raw16, fmat, QP16, KP16, VP16);
    k_logits2<<<NEDGE / 256, 256, 0, stream>>>(eids, isorted, jsorted, zbias, raw16,
        QP16, KP16, gamv, attn);
    k_soft<<<NNODE / 16, 256, 0, stream>>>(rowptr, attn, a16, feat);
    k_aggu<<<NNODE / 4, 256, 0, stream>>>(rowptr, eids, a16, z16, feat);
    k_aggv<<<NNODE / 2, 256, 0, stream>>>(rowptr, jsorted, a16, raw16, VP16, fmat, feat);
    k_gemm<<<dim3(NNODE / 128, SOUT / 128), 256, 0, stream>>>(feat, M2, bo, (float*)d_out,
        NNODE, SOUT, FEAT);
}